// Round 1
// baseline (9148.659 us; speedup 1.0000x reference)
//
#include <hip/hip_runtime.h>
#include <math.h>

#define BATCH 8
#define N_PTS 4096
#define KNN 20
#define EPS_BN 1e-5f
#define SLOPE 0.2f

// ---------------------------------------------------------------------------
// transpose x (B,3,N) -> xt (B,N,3)
__global__ void transpose_x_kernel(const float* __restrict__ x, float* __restrict__ xt) {
    int i = blockIdx.x * blockDim.x + threadIdx.x;
    int total = BATCH * 3 * N_PTS;
    if (i >= total) return;
    int n = i % N_PTS;
    int d = (i / N_PTS) % 3;
    int b = i / (3 * N_PTS);
    xt[((size_t)(b * N_PTS + n)) * 3 + d] = x[i];
}

// ---------------------------------------------------------------------------
// squared norms: sq[b*N+n] = sum_d X[row,d]^2   (one wave per row)
__global__ void sqnorm_kernel(const float* __restrict__ X, int stride, int D,
                              float* __restrict__ sq) {
    int wave = threadIdx.x >> 6;
    int lane = threadIdx.x & 63;
    int row = blockIdx.x * 4 + wave;
    if (row >= BATCH * N_PTS) return;
    const float* xr = X + (size_t)row * stride;
    float s = 0.f;
    for (int d = lane; d < D; d += 64) { float v = xr[d]; s += v * v; }
    #pragma unroll
    for (int off = 32; off > 0; off >>= 1) s += __shfl_down(s, off, 64);
    if (lane == 0) sq[row] = s;
}

// ---------------------------------------------------------------------------
// Fused KNN: 64-row blocks, tiled fp32 distance GEMM + streaming top-20 select.
// grid: (N/64, B), block: 256
__launch_bounds__(256)
__global__ void knn_kernel(const float* __restrict__ X, int stride, int D,
                           const float* __restrict__ sq, int* __restrict__ idxout) {
    __shared__ float As[16][66];    // [dd][row]
    __shared__ float Bs[16][66];    // [dd][col]
    __shared__ float Ss[64][65];    // [col][row]  scores, select reads conflict-free
    __shared__ float lv[64][KNN];
    __shared__ int   li[64][KNN];

    int b = blockIdx.y;
    int row0 = blockIdx.x * 64;
    int tid = threadIdx.x;
    int tx = tid & 15, ty = tid >> 4;

    const float* Xb  = X  + (size_t)b * N_PTS * stride;
    const float* sqb = sq + (size_t)b * N_PTS;

    if (tid < 64) {
        #pragma unroll
        for (int p = 0; p < KNN; ++p) { lv[tid][p] = INFINITY; li[tid][p] = 0; }
    }
    __syncthreads();

    float thr = INFINITY;   // current 20th-best score (only lanes tid<64 use it)

    for (int c0 = 0; c0 < N_PTS; c0 += 64) {
        float acc[4][4];
        #pragma unroll
        for (int i = 0; i < 4; ++i)
            #pragma unroll
            for (int j = 0; j < 4; ++j) acc[i][j] = 0.f;

        for (int kk = 0; kk < D; kk += 16) {
            #pragma unroll
            for (int q = 0; q < 4; ++q) {
                int e = tid + q * 256;           // 0..1023
                int r = e >> 4, dd = e & 15;
                bool ok = (kk + dd) < D;
                As[dd][r] = ok ? Xb[(size_t)(row0 + r) * stride + kk + dd] : 0.f;
                Bs[dd][r] = ok ? Xb[(size_t)(c0   + r) * stride + kk + dd] : 0.f;
            }
            __syncthreads();
            #pragma unroll
            for (int dd = 0; dd < 16; ++dd) {
                float a[4], bb[4];
                #pragma unroll
                for (int i = 0; i < 4; ++i) a[i]  = As[dd][ty * 4 + i];
                #pragma unroll
                for (int j = 0; j < 4; ++j) bb[j] = Bs[dd][tx * 4 + j];
                #pragma unroll
                for (int i = 0; i < 4; ++i)
                    #pragma unroll
                    for (int j = 0; j < 4; ++j) acc[i][j] += a[i] * bb[j];
            }
            __syncthreads();
        }

        // score = sq[col] - 2*dot  (sq[row] constant per row: order-equivalent)
        #pragma unroll
        for (int j = 0; j < 4; ++j) {
            int c = tx * 4 + j;
            float sqc = sqb[c0 + c];
            #pragma unroll
            for (int i = 0; i < 4; ++i)
                Ss[c][ty * 4 + i] = sqc - 2.f * acc[i][j];
        }
        __syncthreads();

        if (tid < 64) {
            int row = tid;
            for (int c = 0; c < 64; ++c) {
                float v = Ss[c][row];
                if (v < thr) {                       // strict: stable ties (lower idx kept)
                    int p = KNN - 1;
                    while (p > 0 && lv[row][p - 1] > v) {
                        lv[row][p] = lv[row][p - 1];
                        li[row][p] = li[row][p - 1];
                        --p;
                    }
                    lv[row][p] = v;
                    li[row][p] = c0 + c;
                    thr = lv[row][KNN - 1];
                }
            }
        }
        __syncthreads();
    }

    if (tid < 64) {
        int* op = idxout + ((size_t)(b * N_PTS + row0 + tid)) * KNN;
        #pragma unroll
        for (int p = 0; p < KNN; ++p) op[p] = li[tid][p];
    }
}

// ---------------------------------------------------------------------------
// Generic tiled fp32 GEMM: out[m,c] = sum_d A[m,d]*Wt[d,c]; optional bn+lrelu.
// grid: (M/64, C/64), block 256
__launch_bounds__(256)
__global__ void gemm_kernel(const float* __restrict__ A, int strideA, int K, int C,
                            const float* __restrict__ Wt,   // (K, C)
                            float* __restrict__ out,        // (M, C)
                            int fuse_bn,
                            const float* __restrict__ g, const float* __restrict__ beta) {
    __shared__ float As[16][66];    // [dd][row]
    __shared__ float Bs[16][64];    // [dd][col]
    int m0 = blockIdx.x * 64;
    int c0 = blockIdx.y * 64;
    int tid = threadIdx.x;
    int tx = tid & 15, ty = tid >> 4;

    float acc[4][4];
    #pragma unroll
    for (int i = 0; i < 4; ++i)
        #pragma unroll
        for (int j = 0; j < 4; ++j) acc[i][j] = 0.f;

    for (int kk = 0; kk < K; kk += 16) {
        #pragma unroll
        for (int q = 0; q < 4; ++q) {
            int e = tid + q * 256;
            {   // A: r = e>>4 (0..63), dd = e&15
                int r = e >> 4, dd = e & 15;
                As[dd][r] = ((kk + dd) < K) ? A[(size_t)(m0 + r) * strideA + kk + dd] : 0.f;
            }
            {   // B: dd = e>>6 (0..15), c = e&63
                int dd = e >> 6, c = e & 63;
                Bs[dd][c] = ((kk + dd) < K) ? Wt[(size_t)(kk + dd) * C + c0 + c] : 0.f;
            }
        }
        __syncthreads();
        #pragma unroll
        for (int dd = 0; dd < 16; ++dd) {
            float a[4], bb[4];
            #pragma unroll
            for (int i = 0; i < 4; ++i) a[i]  = As[dd][ty * 4 + i];
            #pragma unroll
            for (int j = 0; j < 4; ++j) bb[j] = Bs[dd][tx * 4 + j];
            #pragma unroll
            for (int i = 0; i < 4; ++i)
                #pragma unroll
                for (int j = 0; j < 4; ++j) acc[i][j] += a[i] * bb[j];
        }
        __syncthreads();
    }

    #pragma unroll
    for (int i = 0; i < 4; ++i) {
        int m = m0 + ty * 4 + i;
        #pragma unroll
        for (int j = 0; j < 4; ++j) {
            int c = c0 + tx * 4 + j;
            float v = acc[i][j];
            if (fuse_bn) {
                float s = g[c] / sqrtf(1.f + EPS_BN);
                v = v * s + beta[c];
                v = (v >= 0.f) ? v : SLOPE * v;
            }
            out[(size_t)m * C + c] = v;
        }
    }
}

// ---------------------------------------------------------------------------
// weight repacks
__global__ void repack_w_edge(const float* __restrict__ W, int Co, int D,
                              float* __restrict__ Wt) {
    // W (Co, 2D) -> Wt (D, 2Co): Wt[d][o]=W[o][d], Wt[d][Co+o]=W[o][D+d]
    int i = blockIdx.x * blockDim.x + threadIdx.x;
    int tot = D * 2 * Co;
    if (i >= tot) return;
    int c = i % (2 * Co), d = i / (2 * Co);
    Wt[i] = (c < Co) ? W[(size_t)c * 2 * D + d] : W[(size_t)(c - Co) * 2 * D + D + d];
}

__global__ void transpose_w(const float* __restrict__ W, int Co, int D,
                            float* __restrict__ Wt) {
    // W (Co, D) -> Wt (D, Co)
    int i = blockIdx.x * blockDim.x + threadIdx.x;
    if (i >= D * Co) return;
    int c = i % Co, d = i / Co;
    Wt[i] = W[(size_t)c * D + d];
}

// ---------------------------------------------------------------------------
// EdgeConv max-pool epilogue:
// h[b,n,hoff+o] = bn_lrelu( max_j Z[idx[j],o] + C2[n,o] - Z[n,o] )
// grid: (N, B), block: Co
__global__ void pool_kernel(const float* __restrict__ zc2, int Co,
                            const int* __restrict__ idx,
                            const float* __restrict__ g, const float* __restrict__ beta,
                            float* __restrict__ h, int hoff) {
    int n = blockIdx.x, b = blockIdx.y;
    int o = threadIdx.x;
    size_t bn = (size_t)b * N_PTS + n;
    const int* ip = idx + bn * KNN;
    float zn   = zc2[bn * (size_t)(2 * Co) + o];
    float base = zc2[bn * (size_t)(2 * Co) + Co + o] - zn;
    float m = -INFINITY;
    #pragma unroll
    for (int j = 0; j < KNN; ++j) {
        size_t r = (size_t)b * N_PTS + ip[j];
        m = fmaxf(m, zc2[r * (size_t)(2 * Co) + o]);
    }
    float y = m + base;
    float s = g[o] / sqrtf(1.f + EPS_BN);
    y = y * s + beta[o];
    y = (y >= 0.f) ? y : SLOPE * y;
    h[bn * 512 + hoff + o] = y;
}

// ---------------------------------------------------------------------------
// final global max/mean over N: two-stage
__global__ void reduce_partial(const float* __restrict__ y5,
                               float* __restrict__ pmax, float* __restrict__ psum) {
    // grid (16, B), block 512
    int chunk = blockIdx.x, b = blockIdx.y, c = threadIdx.x;
    float mx = -INFINITY, sm = 0.f;
    for (int q = 0; q < 256; ++q) {
        int n = chunk * 256 + q;
        float v = y5[((size_t)b * N_PTS + n) * 512 + c];
        mx = fmaxf(mx, v);
        sm += v;
    }
    pmax[((size_t)b * 16 + chunk) * 512 + c] = mx;
    psum[((size_t)b * 16 + chunk) * 512 + c] = sm;
}

__global__ void reduce_final(const float* __restrict__ pmax,
                             const float* __restrict__ psum,
                             float* __restrict__ out) {
    int i = blockIdx.x * blockDim.x + threadIdx.x;
    if (i >= BATCH * 512) return;
    int b = i / 512, c = i % 512;
    float mx = -INFINITY, sm = 0.f;
    for (int q = 0; q < 16; ++q) {
        mx = fmaxf(mx, pmax[((size_t)b * 16 + q) * 512 + c]);
        sm += psum[((size_t)b * 16 + q) * 512 + c];
    }
    out[(size_t)b * 1024 + c] = mx;
    out[(size_t)b * 1024 + 512 + c] = sm * (1.f / 4096.f);
}

// ---------------------------------------------------------------------------
extern "C" void kernel_launch(void* const* d_in, const int* in_sizes, int n_in,
                              void* d_out, int out_size, void* d_ws, size_t ws_size,
                              hipStream_t stream) {
    const float* x  = (const float*)d_in[0];
    // d_in[1] = k (==20, hardcoded)
    const float* W[5], *gg[5], *bb[5];
    for (int i = 0; i < 5; ++i) {
        W[i]  = (const float*)d_in[2 + 3 * i];
        gg[i] = (const float*)d_in[3 + 3 * i];
        bb[i] = (const float*)d_in[4 + 3 * i];
    }
    float* outp = (float*)d_out;

    // workspace layout (bytes)
    char* wsb = (char*)d_ws;
    size_t off = 0;
    float* xt  = (float*)(wsb + off); off += (size_t)BATCH * N_PTS * 3 * 4;        // 384 KB
    float* sq  = (float*)(wsb + off); off += (size_t)BATCH * N_PTS * 4;            // 128 KB
    int*   idx = (int*)  (wsb + off); off += (size_t)BATCH * N_PTS * KNN * 4;      // 2.5 MB
    float* wt  = (float*)(wsb + off); off += (size_t)512 * 512 * 4;                // 1 MB
    float* h   = (float*)(wsb + off); off += (size_t)BATCH * N_PTS * 512 * 4;      // 64 MB
    float* zc2 = (float*)(wsb + off); off += (size_t)BATCH * N_PTS * 512 * 4;      // 64 MB (also y5)
    float* pmx = (float*)(wsb + off); off += (size_t)BATCH * 16 * 512 * 4;
    float* psm = (float*)(wsb + off); off += (size_t)BATCH * 16 * 512 * 4;
    (void)ws_size; (void)in_sizes; (void)n_in; (void)out_size;

    const int M = BATCH * N_PTS;   // 32768

    transpose_x_kernel<<<(BATCH * 3 * N_PTS + 255) / 256, 256, 0, stream>>>(x, xt);

    struct L { int D, Co, hoff; };
    const L layers[4] = { {3, 64, 0}, {64, 64, 64}, {64, 128, 128}, {128, 256, 256} };

    for (int li = 0; li < 4; ++li) {
        const L& ly = layers[li];
        const float* Xin = (li == 0) ? xt : (h + layers[li - 1].hoff);
        int stride = (li == 0) ? 3 : 512;

        sqnorm_kernel<<<M / 4, 256, 0, stream>>>(Xin, stride, ly.D, sq);
        knn_kernel<<<dim3(N_PTS / 64, BATCH), 256, 0, stream>>>(Xin, stride, ly.D, sq, idx);
        repack_w_edge<<<(ly.D * 2 * ly.Co + 255) / 256, 256, 0, stream>>>(W[li], ly.Co, ly.D, wt);
        gemm_kernel<<<dim3(M / 64, (2 * ly.Co) / 64), 256, 0, stream>>>(
            Xin, stride, ly.D, 2 * ly.Co, wt, zc2, 0, nullptr, nullptr);
        pool_kernel<<<dim3(N_PTS, BATCH), ly.Co, 0, stream>>>(
            zc2, ly.Co, idx, gg[li], bb[li], h, ly.hoff);
    }

    // layer 5: y5 = bn_lrelu(h @ W5^T)   (y5 stored in zc2 buffer)
    transpose_w<<<(512 * 512 + 255) / 256, 256, 0, stream>>>(W[4], 512, 512, wt);
    gemm_kernel<<<dim3(M / 64, 512 / 64), 256, 0, stream>>>(
        h, 512, 512, 512, wt, zc2, 1, gg[4], bb[4]);

    reduce_partial<<<dim3(16, BATCH), 512, 0, stream>>>(zc2, pmx, psm);
    reduce_final<<<(BATCH * 512 + 255) / 256, 256, 0, stream>>>(pmx, psm, outp);
}

// Round 2
// 5917.897 us; speedup vs baseline: 1.5459x; 1.5459x over previous
//
#include <hip/hip_runtime.h>
#include <math.h>

#define BATCH 8
#define N_PTS 4096
#define KNN 20
#define EPS_BN 1e-5f
#define SLOPE 0.2f

// ---------------------------------------------------------------------------
// transpose x (B,3,N) -> xt (B,N,3)
__global__ void transpose_x_kernel(const float* __restrict__ x, float* __restrict__ xt) {
    int i = blockIdx.x * blockDim.x + threadIdx.x;
    int total = BATCH * 3 * N_PTS;
    if (i >= total) return;
    int n = i % N_PTS;
    int d = (i / N_PTS) % 3;
    int b = i / (3 * N_PTS);
    xt[((size_t)(b * N_PTS + n)) * 3 + d] = x[i];
}

// ---------------------------------------------------------------------------
// squared norms (D>=64 path): one wave per row
__global__ void sqnorm_kernel(const float* __restrict__ X, int stride, int D,
                              float* __restrict__ sq) {
    int wave = threadIdx.x >> 6;
    int lane = threadIdx.x & 63;
    int row = blockIdx.x * 4 + wave;
    if (row >= BATCH * N_PTS) return;
    const float* xr = X + (size_t)row * stride;
    float s = 0.f;
    for (int d = lane; d < D; d += 64) { float v = xr[d]; s += v * v; }
    #pragma unroll
    for (int off = 32; off > 0; off >>= 1) s += __shfl_down(s, off, 64);
    if (lane == 0) sq[row] = s;
}

// D==3 path: one thread per row
__global__ void sqnorm3_kernel(const float* __restrict__ X, float* __restrict__ sq) {
    int i = blockIdx.x * blockDim.x + threadIdx.x;
    if (i >= BATCH * N_PTS) return;
    const float* p = X + (size_t)i * 3;
    sq[i] = p[0] * p[0] + p[1] * p[1] + p[2] * p[2];
}

// ---------------------------------------------------------------------------
// Fused KNN: 64x64 register-tiled fp32 distance GEMM + parallel streaming
// top-20 (4 threads/row, register lists, final lex merge).
// grid: (N/64, B), block: 256
template<int DCH>
__launch_bounds__(256)
__global__ void knn_kernel(const float* __restrict__ X, int stride, int D,
                           const float* __restrict__ sq, int* __restrict__ idxout) {
    __shared__ float As[16][68];    // [dd][row]  stride 68: 16B-aligned rows-of-4
    __shared__ float Bs[16][68];    // [dd][col]
    __shared__ float Ss[64][65];    // [row][col] scores
    __shared__ float Mv[64][3 * KNN + 1];   // merge dump (slices 1..3), odd stride
    __shared__ int   Mi[64][3 * KNN + 1];

    const int b = blockIdx.y;
    const int row0 = blockIdx.x * 64;
    const int tid = threadIdx.x;
    const int tx = tid & 15, ty = tid >> 4;
    const int r = tid & 63, s = tid >> 6;   // selection: row r, col-slice s

    const float* Xb  = X  + (size_t)b * N_PTS * stride;
    const float* sqb = sq + (size_t)b * N_PTS;

    // per-thread top-20 (registers; constant indices only -> promoted)
    float fv[KNN]; int fi[KNN];
    #pragma unroll
    for (int p = 0; p < KNN; ++p) { fv[p] = INFINITY; fi[p] = 0x7FFFFFFF; }

    for (int c0 = 0; c0 < N_PTS; c0 += 64) {
        float acc[4][4];
        #pragma unroll
        for (int i = 0; i < 4; ++i)
            #pragma unroll
            for (int j = 0; j < 4; ++j) acc[i][j] = 0.f;

        for (int kk = 0; kk < D; kk += DCH) {
            #pragma unroll
            for (int q = 0; q < DCH / 4; ++q) {
                int e = tid + q * 256;          // 64*DCH elements per chunk
                int rr = e / DCH, dd = e % DCH;
                bool ok = (kk + dd) < D;
                As[dd][rr] = ok ? Xb[(size_t)(row0 + rr) * stride + kk + dd] : 0.f;
                Bs[dd][rr] = ok ? Xb[(size_t)(c0   + rr) * stride + kk + dd] : 0.f;
            }
            __syncthreads();
            #pragma unroll
            for (int dd = 0; dd < DCH; ++dd) {
                float a[4], bb[4];
                #pragma unroll
                for (int i = 0; i < 4; ++i) a[i]  = As[dd][ty * 4 + i];
                #pragma unroll
                for (int j = 0; j < 4; ++j) bb[j] = Bs[dd][tx * 4 + j];
                #pragma unroll
                for (int i = 0; i < 4; ++i)
                    #pragma unroll
                    for (int j = 0; j < 4; ++j) acc[i][j] += a[i] * bb[j];
            }
            __syncthreads();
        }

        // scores -> Ss[row][col]; score = sq[col] - 2*dot (sq[row] dropped:
        // constant per row, order-preserving). Lane-rotated i to spread banks.
        float sqc[4];
        #pragma unroll
        for (int j = 0; j < 4; ++j) sqc[j] = sqb[c0 + tx * 4 + j];
        #pragma unroll
        for (int i0 = 0; i0 < 4; ++i0) {
            int i = (i0 + tx) & 3;
            #pragma unroll
            for (int j = 0; j < 4; ++j)
                Ss[ty * 4 + i][tx * 4 + j] = sqc[j] - 2.f * acc[i][j];
        }
        __syncthreads();

        // streaming selection: thread (r,s) scans cols [s*16, s*16+16) of tile.
        // Ascending index within thread + strict '<' == lex-stable top-k.
        const int cbase = s * 16;
        #pragma unroll 1
        for (int c = 0; c < 16; ++c) {
            float v = Ss[r][cbase + c];
            if (__builtin_expect(v < fv[KNN - 1], 0)) {
                fv[KNN - 1] = v; fi[KNN - 1] = c0 + cbase + c;
                #pragma unroll
                for (int p = KNN - 1; p > 0; --p) {
                    float va = fv[p - 1], vb = fv[p];
                    int   ia = fi[p - 1], ib = fi[p];
                    bool sw = vb < va;
                    fv[p - 1] = sw ? vb : va; fv[p] = sw ? va : vb;
                    fi[p - 1] = sw ? ib : ia; fi[p] = sw ? ia : ib;
                }
            }
        }
        __syncthreads();
    }

    // dump slice lists 1..3, merge on threads 0..63 (lex (val,idx) compare
    // reproduces lax.top_k stable tie-breaking; only the SET matters).
    if (s > 0) {
        #pragma unroll
        for (int p = 0; p < KNN; ++p) {
            Mv[r][(s - 1) * KNN + p] = fv[p];
            Mi[r][(s - 1) * KNN + p] = fi[p];
        }
    }
    __syncthreads();
    if (tid < 64) {
        #pragma unroll 1
        for (int q = 0; q < 3 * KNN; ++q) {
            float v = Mv[tid][q]; int ci = Mi[tid][q];
            bool ins = (v < fv[KNN - 1]) || (v == fv[KNN - 1] && ci < fi[KNN - 1]);
            if (__builtin_expect(ins, 0)) {
                fv[KNN - 1] = v; fi[KNN - 1] = ci;
                #pragma unroll
                for (int p = KNN - 1; p > 0; --p) {
                    float va = fv[p - 1], vb = fv[p];
                    int   ia = fi[p - 1], ib = fi[p];
                    bool sw = (vb < va) || (vb == va && ib < ia);
                    fv[p - 1] = sw ? vb : va; fv[p] = sw ? va : vb;
                    fi[p - 1] = sw ? ib : ia; fi[p] = sw ? ia : ib;
                }
            }
        }
        int* op = idxout + ((size_t)(b * N_PTS + row0 + tid)) * KNN;
        #pragma unroll
        for (int p = 0; p < KNN; ++p) op[p] = fi[p];
    }
}

// ---------------------------------------------------------------------------
// Generic tiled fp32 GEMM: out[m,c] = sum_d A[m,d]*Wt[d,c]; optional bn+lrelu.
__launch_bounds__(256)
__global__ void gemm_kernel(const float* __restrict__ A, int strideA, int K, int C,
                            const float* __restrict__ Wt,   // (K, C)
                            float* __restrict__ out,        // (M, C)
                            int fuse_bn,
                            const float* __restrict__ g, const float* __restrict__ beta) {
    __shared__ float As[16][68];
    __shared__ float Bs[16][64];
    int m0 = blockIdx.x * 64;
    int c0 = blockIdx.y * 64;
    int tid = threadIdx.x;
    int tx = tid & 15, ty = tid >> 4;

    float acc[4][4];
    #pragma unroll
    for (int i = 0; i < 4; ++i)
        #pragma unroll
        for (int j = 0; j < 4; ++j) acc[i][j] = 0.f;

    for (int kk = 0; kk < K; kk += 16) {
        #pragma unroll
        for (int q = 0; q < 4; ++q) {
            int e = tid + q * 256;
            {
                int rr = e >> 4, dd = e & 15;
                As[dd][rr] = ((kk + dd) < K) ? A[(size_t)(m0 + rr) * strideA + kk + dd] : 0.f;
            }
            {
                int dd = e >> 6, c = e & 63;
                Bs[dd][c] = ((kk + dd) < K) ? Wt[(size_t)(kk + dd) * C + c0 + c] : 0.f;
            }
        }
        __syncthreads();
        #pragma unroll
        for (int dd = 0; dd < 16; ++dd) {
            float a[4], bb[4];
            #pragma unroll
            for (int i = 0; i < 4; ++i) a[i]  = As[dd][ty * 4 + i];
            #pragma unroll
            for (int j = 0; j < 4; ++j) bb[j] = Bs[dd][tx * 4 + j];
            #pragma unroll
            for (int i = 0; i < 4; ++i)
                #pragma unroll
                for (int j = 0; j < 4; ++j) acc[i][j] += a[i] * bb[j];
        }
        __syncthreads();
    }

    #pragma unroll
    for (int i = 0; i < 4; ++i) {
        int m = m0 + ty * 4 + i;
        #pragma unroll
        for (int j = 0; j < 4; ++j) {
            int c = c0 + tx * 4 + j;
            float v = acc[i][j];
            if (fuse_bn) {
                float sc = g[c] / sqrtf(1.f + EPS_BN);
                v = v * sc + beta[c];
                v = (v >= 0.f) ? v : SLOPE * v;
            }
            out[(size_t)m * C + c] = v;
        }
    }
}

// ---------------------------------------------------------------------------
// weight repacks
__global__ void repack_w_edge(const float* __restrict__ W, int Co, int D,
                              float* __restrict__ Wt) {
    int i = blockIdx.x * blockDim.x + threadIdx.x;
    int tot = D * 2 * Co;
    if (i >= tot) return;
    int c = i % (2 * Co), d = i / (2 * Co);
    Wt[i] = (c < Co) ? W[(size_t)c * 2 * D + d] : W[(size_t)(c - Co) * 2 * D + D + d];
}

__global__ void transpose_w(const float* __restrict__ W, int Co, int D,
                            float* __restrict__ Wt) {
    int i = blockIdx.x * blockDim.x + threadIdx.x;
    if (i >= D * Co) return;
    int c = i % Co, d = i / Co;
    Wt[i] = W[(size_t)c * D + d];
}

// ---------------------------------------------------------------------------
// EdgeConv max-pool epilogue:
// h[b,n,hoff+o] = bn_lrelu( max_j Z[idx[j],o] + C2[n,o] - Z[n,o] )
__global__ void pool_kernel(const float* __restrict__ zc2, int Co,
                            const int* __restrict__ idx,
                            const float* __restrict__ g, const float* __restrict__ beta,
                            float* __restrict__ h, int hoff) {
    int n = blockIdx.x, b = blockIdx.y;
    int o = threadIdx.x;
    size_t bn = (size_t)b * N_PTS + n;
    const int* ip = idx + bn * KNN;
    float zn   = zc2[bn * (size_t)(2 * Co) + o];
    float base = zc2[bn * (size_t)(2 * Co) + Co + o] - zn;
    float m = -INFINITY;
    #pragma unroll
    for (int j = 0; j < KNN; ++j) {
        size_t rr = (size_t)b * N_PTS + ip[j];
        m = fmaxf(m, zc2[rr * (size_t)(2 * Co) + o]);
    }
    float y = m + base;
    float sc = g[o] / sqrtf(1.f + EPS_BN);
    y = y * sc + beta[o];
    y = (y >= 0.f) ? y : SLOPE * y;
    h[bn * 512 + hoff + o] = y;
}

// ---------------------------------------------------------------------------
// final global max/mean over N: two-stage
__global__ void reduce_partial(const float* __restrict__ y5,
                               float* __restrict__ pmax, float* __restrict__ psum) {
    int chunk = blockIdx.x, b = blockIdx.y, c = threadIdx.x;
    float mx = -INFINITY, sm = 0.f;
    for (int q = 0; q < 256; ++q) {
        int n = chunk * 256 + q;
        float v = y5[((size_t)b * N_PTS + n) * 512 + c];
        mx = fmaxf(mx, v);
        sm += v;
    }
    pmax[((size_t)b * 16 + chunk) * 512 + c] = mx;
    psum[((size_t)b * 16 + chunk) * 512 + c] = sm;
}

__global__ void reduce_final(const float* __restrict__ pmax,
                             const float* __restrict__ psum,
                             float* __restrict__ out) {
    int i = blockIdx.x * blockDim.x + threadIdx.x;
    if (i >= BATCH * 512) return;
    int b = i / 512, c = i % 512;
    float mx = -INFINITY, sm = 0.f;
    for (int q = 0; q < 16; ++q) {
        mx = fmaxf(mx, pmax[((size_t)b * 16 + q) * 512 + c]);
        sm += psum[((size_t)b * 16 + q) * 512 + c];
    }
    out[(size_t)b * 1024 + c] = mx;
    out[(size_t)b * 1024 + 512 + c] = sm * (1.f / 4096.f);
}

// ---------------------------------------------------------------------------
extern "C" void kernel_launch(void* const* d_in, const int* in_sizes, int n_in,
                              void* d_out, int out_size, void* d_ws, size_t ws_size,
                              hipStream_t stream) {
    const float* x  = (const float*)d_in[0];
    const float* W[5], *gg[5], *bb[5];
    for (int i = 0; i < 5; ++i) {
        W[i]  = (const float*)d_in[2 + 3 * i];
        gg[i] = (const float*)d_in[3 + 3 * i];
        bb[i] = (const float*)d_in[4 + 3 * i];
    }
    float* outp = (float*)d_out;

    char* wsb = (char*)d_ws;
    size_t off = 0;
    float* xt  = (float*)(wsb + off); off += (size_t)BATCH * N_PTS * 3 * 4;
    float* sq  = (float*)(wsb + off); off += (size_t)BATCH * N_PTS * 4;
    int*   idx = (int*)  (wsb + off); off += (size_t)BATCH * N_PTS * KNN * 4;
    float* wt  = (float*)(wsb + off); off += (size_t)512 * 512 * 4;
    float* h   = (float*)(wsb + off); off += (size_t)BATCH * N_PTS * 512 * 4;
    float* zc2 = (float*)(wsb + off); off += (size_t)BATCH * N_PTS * 512 * 4;
    float* pmx = (float*)(wsb + off); off += (size_t)BATCH * 16 * 512 * 4;
    float* psm = (float*)(wsb + off); off += (size_t)BATCH * 16 * 512 * 4;
    (void)ws_size; (void)in_sizes; (void)n_in; (void)out_size;

    const int M = BATCH * N_PTS;

    transpose_x_kernel<<<(BATCH * 3 * N_PTS + 255) / 256, 256, 0, stream>>>(x, xt);

    struct L { int D, Co, hoff; };
    const L layers[4] = { {3, 64, 0}, {64, 64, 64}, {64, 128, 128}, {128, 256, 256} };

    for (int li = 0; li < 4; ++li) {
        const L& ly = layers[li];
        const float* Xin = (li == 0) ? xt : (h + layers[li - 1].hoff);
        int stride = (li == 0) ? 3 : 512;

        if (li == 0) {
            sqnorm3_kernel<<<(M + 255) / 256, 256, 0, stream>>>(Xin, sq);
            knn_kernel<4><<<dim3(N_PTS / 64, BATCH), 256, 0, stream>>>(Xin, stride, ly.D, sq, idx);
        } else {
            sqnorm_kernel<<<M / 4, 256, 0, stream>>>(Xin, stride, ly.D, sq);
            knn_kernel<16><<<dim3(N_PTS / 64, BATCH), 256, 0, stream>>>(Xin, stride, ly.D, sq, idx);
        }
        repack_w_edge<<<(ly.D * 2 * ly.Co + 255) / 256, 256, 0, stream>>>(W[li], ly.Co, ly.D, wt);
        gemm_kernel<<<dim3(M / 64, (2 * ly.Co) / 64), 256, 0, stream>>>(
            Xin, stride, ly.D, 2 * ly.Co, wt, zc2, 0, nullptr, nullptr);
        pool_kernel<<<dim3(N_PTS, BATCH), ly.Co, 0, stream>>>(
            zc2, ly.Co, idx, gg[li], bb[li], h, ly.hoff);
    }

    transpose_w<<<(512 * 512 + 255) / 256, 256, 0, stream>>>(W[4], 512, 512, wt);
    gemm_kernel<<<dim3(M / 64, 512 / 64), 256, 0, stream>>>(
        h, 512, 512, 512, wt, zc2, 1, gg[4], bb[4]);

    reduce_partial<<<dim3(16, BATCH), 512, 0, stream>>>(zc2, pmx, psm);
    reduce_final<<<(BATCH * 512 + 255) / 256, 256, 0, stream>>>(pmx, psm, outp);
}

// Round 3
// 4580.870 us; speedup vs baseline: 1.9971x; 1.2919x over previous
//
#include <hip/hip_runtime.h>
#include <math.h>

#define BATCH 8
#define N_PTS 4096
#define KNN 20
#define EPS_BN 1e-5f
#define SLOPE 0.2f
#define M_ROWS (BATCH * N_PTS)

typedef __attribute__((ext_vector_type(8))) short short8;     // bf16 x8 (4 VGPR)
typedef __attribute__((ext_vector_type(4))) float float4v;    // fp32 x4 acc

__device__ __forceinline__ unsigned short f2bf(float f) {
    unsigned u = __float_as_uint(f);
    unsigned r = (u + 0x7FFFu + ((u >> 16) & 1u)) >> 16;
    return (unsigned short)r;
}
__device__ __forceinline__ float bf2f(unsigned short h) {
    return __uint_as_float((unsigned)h << 16);
}

// ---------------------------------------------------------------------------
// x (B,3,N) fp32 -> x1h/x1l (M,32) bf16 split (zero-padded), + sq norms
__global__ void convert_x1(const float* __restrict__ x,
                           unsigned short* __restrict__ xh, unsigned short* __restrict__ xl,
                           float* __restrict__ sq) {
    int i = blockIdx.x * blockDim.x + threadIdx.x;
    if (i >= M_ROWS) return;
    int b = i / N_PTS, n = i % N_PTS;
    float v[3], s = 0.f;
    #pragma unroll
    for (int d = 0; d < 3; ++d) {
        v[d] = x[((size_t)b * 3 + d) * N_PTS + n];
        s += v[d] * v[d];
    }
    sq[i] = s;
    #pragma unroll
    for (int d = 0; d < 32; ++d) {
        float f = (d < 3) ? v[d] : 0.f;
        unsigned short h = f2bf(f);
        xh[(size_t)i * 32 + d] = h;
        xl[(size_t)i * 32 + d] = f2bf(f - bf2f(h));
    }
}

// sq norms from bf16 hi/lo feature rows (stride 512, offset pre-applied by caller)
__global__ void sqnorm_hl(const unsigned short* __restrict__ hh,
                          const unsigned short* __restrict__ hl,
                          int D, float* __restrict__ sq) {
    int w = threadIdx.x >> 6, lane = threadIdx.x & 63;
    int row = blockIdx.x * 4 + w;
    if (row >= M_ROWS) return;
    const unsigned short* ph = hh + (size_t)row * 512;
    const unsigned short* pl = hl + (size_t)row * 512;
    float s = 0.f;
    for (int d = lane; d < D; d += 64) {
        float v = bf2f(ph[d]) + bf2f(pl[d]);
        s += v * v;
    }
    #pragma unroll
    for (int off = 32; off > 0; off >>= 1) s += __shfl_down(s, off, 64);
    if (lane == 0) sq[row] = s;
}

// ---------------------------------------------------------------------------
// weight repacks -> bf16 hi/lo, B-operand layout [C][KP] (k contiguous)
__global__ void repack_edge_split(const float* __restrict__ W, int Co, int D, int KP,
                                  unsigned short* __restrict__ Wh, unsigned short* __restrict__ Wl) {
    int i = blockIdx.x * blockDim.x + threadIdx.x;
    int tot = 2 * Co * KP;
    if (i >= tot) return;
    int r = i / KP, d = i % KP;
    float v = 0.f;
    if (d < D) v = (r < Co) ? W[(size_t)r * 2 * D + d] : W[(size_t)(r - Co) * 2 * D + D + d];
    unsigned short h = f2bf(v);
    Wh[i] = h; Wl[i] = f2bf(v - bf2f(h));
}

__global__ void repack_w5_split(const float* __restrict__ W,
                                unsigned short* __restrict__ Wh, unsigned short* __restrict__ Wl) {
    int i = blockIdx.x * blockDim.x + threadIdx.x;
    if (i >= 512 * 512) return;
    float v = W[i];
    unsigned short h = f2bf(v);
    Wh[i] = h; Wl[i] = f2bf(v - bf2f(h));
}

// ---------------------------------------------------------------------------
// MFMA KNN: block = 128 rows, sweeps cols in 64-chunks.
// A frags in registers (hi/lo), B tile staged in LDS, 3-pass bf16 split MFMA.
// grid: (N/128, B), block 256 (4 waves, each 32 rows x 64 cols).
template<int DPAD>
__launch_bounds__(256)
__global__ void knn_mfma(const unsigned short* __restrict__ Xh,
                         const unsigned short* __restrict__ Xl,
                         int strideX,
                         const float* __restrict__ sq, int* __restrict__ idxout) {
    constexpr int KS = DPAD / 32;         // mfma k-steps
    constexpr int BST = DPAD + 8;         // LDS row stride (ushorts), 16B-multiple
    constexpr int C8 = DPAD / 8;
    __shared__ unsigned short BhS[64 * BST];
    __shared__ unsigned short BlS[64 * BST];
    __shared__ float Ss[128 * 65];        // scores [row][col]; aliased for merge
    __shared__ float sqs[64];

    const int b = blockIdx.y;
    const int row0 = blockIdx.x * 128;
    const int tid = threadIdx.x;
    const int w = tid >> 6, lane = tid & 63;
    const int n = lane & 15, q = lane >> 4;

    const unsigned short* Xhb = Xh + (size_t)b * N_PTS * strideX;
    const unsigned short* Xlb = Xl + (size_t)b * N_PTS * strideX;
    const float* sqb = sq + (size_t)b * N_PTS;

    // A fragments (registers), rows w*32 + rt*16 + n
    short8 ah[2][KS], al[2][KS];
    #pragma unroll
    for (int rt = 0; rt < 2; ++rt)
        #pragma unroll
        for (int ks = 0; ks < KS; ++ks) {
            size_t o = (size_t)(row0 + w * 32 + rt * 16 + n) * strideX + ks * 32 + q * 8;
            ah[rt][ks] = *(const short8*)(Xhb + o);
            al[rt][ks] = *(const short8*)(Xlb + o);
        }

    // per-thread top-20 in registers
    float fv[KNN]; int fi[KNN];
    #pragma unroll
    for (int p = 0; p < KNN; ++p) { fv[p] = INFINITY; fi[p] = 0x7FFFFFFF; }

    const int r = tid & 127, sl = tid >> 7;     // selection: row r, col-slice sl

    for (int c0 = 0; c0 < N_PTS; c0 += 64) {
        __syncthreads();
        // stage B tile (64 cols x DPAD, hi+lo)
        for (int t = tid; t < 64 * C8; t += 256) {
            int rr = t / C8, c8 = t % C8;
            size_t o = (size_t)(c0 + rr) * strideX + c8 * 8;
            *(short8*)&BhS[rr * BST + c8 * 8] = *(const short8*)(Xhb + o);
            *(short8*)&BlS[rr * BST + c8 * 8] = *(const short8*)(Xlb + o);
        }
        if (tid < 64) sqs[tid] = sqb[c0 + tid];
        __syncthreads();

        float4v acc[2][4];
        #pragma unroll
        for (int rt = 0; rt < 2; ++rt)
            #pragma unroll
            for (int ct = 0; ct < 4; ++ct)
                acc[rt][ct] = (float4v){0.f, 0.f, 0.f, 0.f};

        #pragma unroll
        for (int ks = 0; ks < KS; ++ks) {
            #pragma unroll
            for (int ct = 0; ct < 4; ++ct) {
                short8 bh = *(const short8*)&BhS[(ct * 16 + n) * BST + ks * 32 + q * 8];
                short8 bl = *(const short8*)&BlS[(ct * 16 + n) * BST + ks * 32 + q * 8];
                #pragma unroll
                for (int rt = 0; rt < 2; ++rt) {
                    acc[rt][ct] = __builtin_amdgcn_mfma_f32_16x16x32_bf16(ah[rt][ks], bh, acc[rt][ct], 0, 0, 0);
                    acc[rt][ct] = __builtin_amdgcn_mfma_f32_16x16x32_bf16(al[rt][ks], bh, acc[rt][ct], 0, 0, 0);
                    acc[rt][ct] = __builtin_amdgcn_mfma_f32_16x16x32_bf16(ah[rt][ks], bl, acc[rt][ct], 0, 0, 0);
                }
            }
        }

        // scores -> Ss[row][col]; score = sq[col] - 2*dot
        #pragma unroll
        for (int rt = 0; rt < 2; ++rt)
            #pragma unroll
            for (int ct = 0; ct < 4; ++ct) {
                float sc = sqs[ct * 16 + n];
                #pragma unroll
                for (int e = 0; e < 4; ++e)
                    Ss[(w * 32 + rt * 16 + q * 4 + e) * 65 + ct * 16 + n] = sc - 2.f * acc[rt][ct][e];
            }
        __syncthreads();

        // streaming selection: thread (r, sl) scans 32 cols
        const int cbase = sl * 32;
        #pragma unroll 1
        for (int c = 0; c < 32; ++c) {
            float v = Ss[r * 65 + cbase + c];
            if (__builtin_expect(v < fv[KNN - 1], 0)) {
                fv[KNN - 1] = v; fi[KNN - 1] = c0 + cbase + c;
                #pragma unroll
                for (int p = KNN - 1; p > 0; --p) {
                    float va = fv[p - 1], vb = fv[p];
                    int ia = fi[p - 1], ib = fi[p];
                    bool sw = vb < va;
                    fv[p - 1] = sw ? vb : va; fv[p] = sw ? va : vb;
                    fi[p - 1] = sw ? ib : ia; fi[p] = sw ? ia : ib;
                }
            }
        }
    }
    __syncthreads();

    // slice-1 threads dump into aliased Ss region (indices bit-cast to float)
    if (sl == 1) {
        #pragma unroll
        for (int p = 0; p < KNN; ++p) {
            Ss[r * 21 + p] = fv[p];
            Ss[4096 + r * 21 + p] = __int_as_float(fi[p]);
        }
    }
    __syncthreads();
    if (tid < 128) {
        #pragma unroll 1
        for (int qq = 0; qq < KNN; ++qq) {
            float v = Ss[tid * 21 + qq];
            int ci = __float_as_int(Ss[4096 + tid * 21 + qq]);
            bool ins = (v < fv[KNN - 1]) || (v == fv[KNN - 1] && ci < fi[KNN - 1]);
            if (ins) {
                fv[KNN - 1] = v; fi[KNN - 1] = ci;
                #pragma unroll
                for (int p = KNN - 1; p > 0; --p) {
                    float va = fv[p - 1], vb = fv[p];
                    int ia = fi[p - 1], ib = fi[p];
                    bool sw = (vb < va) || (vb == va && ib < ia);
                    fv[p - 1] = sw ? vb : va; fv[p] = sw ? va : vb;
                    fi[p - 1] = sw ? ib : ia; fi[p] = sw ? ia : ib;
                }
            }
        }
        int* op = idxout + ((size_t)(b * N_PTS + row0 + tid)) * KNN;
        #pragma unroll
        for (int p = 0; p < KNN; ++p) op[p] = fi[p];
    }
}

// ---------------------------------------------------------------------------
// MFMA feature GEMM: out[m,c] = sum_k A[m,k]*W[c,k], bf16 hi/lo 3-pass.
// grid: (C/128, M/128), block 256; wave = 32 rows x 128 cols.
__launch_bounds__(256)
__global__ void fgemm(const unsigned short* __restrict__ Ah, const unsigned short* __restrict__ Al,
                      int strideA, int K,
                      const unsigned short* __restrict__ Wh, const unsigned short* __restrict__ Wl,
                      int C, float* __restrict__ out, int fuse_bn,
                      const float* __restrict__ g, const float* __restrict__ beta) {
    __shared__ unsigned short AhS[128 * 40];
    __shared__ unsigned short AlS[128 * 40];
    __shared__ unsigned short BhS[128 * 40];
    __shared__ unsigned short BlS[128 * 40];

    const int c0 = blockIdx.x * 128;
    const int m0 = blockIdx.y * 128;
    const int tid = threadIdx.x;
    const int w = tid >> 6, lane = tid & 63;
    const int n = lane & 15, q = lane >> 4;

    float4v acc[2][8];
    #pragma unroll
    for (int rt = 0; rt < 2; ++rt)
        #pragma unroll
        for (int ct = 0; ct < 8; ++ct) acc[rt][ct] = (float4v){0.f, 0.f, 0.f, 0.f};

    for (int kk = 0; kk < K; kk += 32) {
        __syncthreads();
        for (int t = tid; t < 512; t += 256) {
            int rr = t >> 2, c8 = t & 3;
            size_t oa = (size_t)(m0 + rr) * strideA + kk + c8 * 8;
            *(short8*)&AhS[rr * 40 + c8 * 8] = *(const short8*)(Ah + oa);
            *(short8*)&AlS[rr * 40 + c8 * 8] = *(const short8*)(Al + oa);
            size_t ob = (size_t)(c0 + rr) * K + kk + c8 * 8;
            *(short8*)&BhS[rr * 40 + c8 * 8] = *(const short8*)(Wh + ob);
            *(short8*)&BlS[rr * 40 + c8 * 8] = *(const short8*)(Wl + ob);
        }
        __syncthreads();

        short8 af[2][2];
        #pragma unroll
        for (int rt = 0; rt < 2; ++rt) {
            af[rt][0] = *(const short8*)&AhS[(w * 32 + rt * 16 + n) * 40 + q * 8];
            af[rt][1] = *(const short8*)&AlS[(w * 32 + rt * 16 + n) * 40 + q * 8];
        }
        #pragma unroll
        for (int ct = 0; ct < 8; ++ct) {
            short8 bh = *(const short8*)&BhS[(ct * 16 + n) * 40 + q * 8];
            short8 bl = *(const short8*)&BlS[(ct * 16 + n) * 40 + q * 8];
            #pragma unroll
            for (int rt = 0; rt < 2; ++rt) {
                acc[rt][ct] = __builtin_amdgcn_mfma_f32_16x16x32_bf16(af[rt][0], bh, acc[rt][ct], 0, 0, 0);
                acc[rt][ct] = __builtin_amdgcn_mfma_f32_16x16x32_bf16(af[rt][1], bh, acc[rt][ct], 0, 0, 0);
                acc[rt][ct] = __builtin_amdgcn_mfma_f32_16x16x32_bf16(af[rt][0], bl, acc[rt][ct], 0, 0, 0);
            }
        }
    }

    #pragma unroll
    for (int rt = 0; rt < 2; ++rt)
        #pragma unroll
        for (int ct = 0; ct < 8; ++ct) {
            int c = c0 + ct * 16 + n;
            float sc = 1.f, bt = 0.f;
            if (fuse_bn) { sc = g[c] / sqrtf(1.f + EPS_BN); bt = beta[c]; }
            #pragma unroll
            for (int e = 0; e < 4; ++e) {
                int m = m0 + w * 32 + rt * 16 + q * 4 + e;
                float v = acc[rt][ct][e];
                if (fuse_bn) { v = v * sc + bt; v = (v >= 0.f) ? v : SLOPE * v; }
                out[(size_t)m * C + c] = v;
            }
        }
}

// ---------------------------------------------------------------------------
// EdgeConv max-pool epilogue -> bf16 hi/lo feature rows
__global__ void pool_kernel(const float* __restrict__ zc2, int Co,
                            const int* __restrict__ idx,
                            const float* __restrict__ g, const float* __restrict__ beta,
                            unsigned short* __restrict__ hh, unsigned short* __restrict__ hl,
                            int hoff) {
    int n = blockIdx.x, b = blockIdx.y;
    int o = threadIdx.x;
    size_t bn = (size_t)b * N_PTS + n;
    const int* ip = idx + bn * KNN;
    float zn   = zc2[bn * (size_t)(2 * Co) + o];
    float base = zc2[bn * (size_t)(2 * Co) + Co + o] - zn;
    float m = -INFINITY;
    #pragma unroll
    for (int j = 0; j < KNN; ++j) {
        size_t rr = (size_t)b * N_PTS + ip[j];
        m = fmaxf(m, zc2[rr * (size_t)(2 * Co) + o]);
    }
    float y = m + base;
    float sc = g[o] / sqrtf(1.f + EPS_BN);
    y = y * sc + beta[o];
    y = (y >= 0.f) ? y : SLOPE * y;
    unsigned short h = f2bf(y);
    hh[bn * 512 + hoff + o] = h;
    hl[bn * 512 + hoff + o] = f2bf(y - bf2f(h));
}

// ---------------------------------------------------------------------------
// final global max/mean over N: two-stage
__global__ void reduce_partial(const float* __restrict__ y5,
                               float* __restrict__ pmax, float* __restrict__ psum) {
    int chunk = blockIdx.x, b = blockIdx.y, c = threadIdx.x;
    float mx = -INFINITY, sm = 0.f;
    for (int qq = 0; qq < 256; ++qq) {
        int n = chunk * 256 + qq;
        float v = y5[((size_t)b * N_PTS + n) * 512 + c];
        mx = fmaxf(mx, v);
        sm += v;
    }
    pmax[((size_t)b * 16 + chunk) * 512 + c] = mx;
    psum[((size_t)b * 16 + chunk) * 512 + c] = sm;
}

__global__ void reduce_final(const float* __restrict__ pmax,
                             const float* __restrict__ psum,
                             float* __restrict__ out) {
    int i = blockIdx.x * blockDim.x + threadIdx.x;
    if (i >= BATCH * 512) return;
    int b = i / 512, c = i % 512;
    float mx = -INFINITY, sm = 0.f;
    for (int qq = 0; qq < 16; ++qq) {
        mx = fmaxf(mx, pmax[((size_t)b * 16 + qq) * 512 + c]);
        sm += psum[((size_t)b * 16 + qq) * 512 + c];
    }
    out[(size_t)b * 1024 + c] = mx;
    out[(size_t)b * 1024 + 512 + c] = sm * (1.f / 4096.f);
}

// ---------------------------------------------------------------------------
extern "C" void kernel_launch(void* const* d_in, const int* in_sizes, int n_in,
                              void* d_out, int out_size, void* d_ws, size_t ws_size,
                              hipStream_t stream) {
    const float* x = (const float*)d_in[0];
    const float* W[5], *gg[5], *bb[5];
    for (int i = 0; i < 5; ++i) {
        W[i]  = (const float*)d_in[2 + 3 * i];
        gg[i] = (const float*)d_in[3 + 3 * i];
        bb[i] = (const float*)d_in[4 + 3 * i];
    }
    float* outp = (float*)d_out;

    char* wsb = (char*)d_ws;
    size_t off = 0;
    unsigned short* x1h = (unsigned short*)(wsb + off); off += (size_t)M_ROWS * 32 * 2;   // 2 MB
    unsigned short* x1l = (unsigned short*)(wsb + off); off += (size_t)M_ROWS * 32 * 2;   // 2 MB
    float* sq = (float*)(wsb + off); off += (size_t)M_ROWS * 4;                           // 128 KB
    int*   idx = (int*)(wsb + off); off += (size_t)M_ROWS * KNN * 4;                      // 2.5 MB
    unsigned short* Wh = (unsigned short*)(wsb + off); off += (size_t)512 * 512 * 2;      // 512 KB
    unsigned short* Wl = (unsigned short*)(wsb + off); off += (size_t)512 * 512 * 2;      // 512 KB
    unsigned short* hh = (unsigned short*)(wsb + off); off += (size_t)M_ROWS * 512 * 2;   // 32 MB
    unsigned short* hl = (unsigned short*)(wsb + off); off += (size_t)M_ROWS * 512 * 2;   // 32 MB
    float* zc2 = (float*)(wsb + off); off += (size_t)M_ROWS * 512 * 4;                    // 64 MB
    float* pmx = (float*)(wsb + off); off += (size_t)BATCH * 16 * 512 * 4;
    float* psm = (float*)(wsb + off); off += (size_t)BATCH * 16 * 512 * 4;
    (void)ws_size; (void)in_sizes; (void)n_in; (void)out_size;

    convert_x1<<<(M_ROWS + 255) / 256, 256, 0, stream>>>(x, x1h, x1l, sq);

    struct L { int D, Co, KP, hoff; };
    const L layers[4] = { {3, 64, 32, 0}, {64, 64, 64, 64}, {64, 128, 64, 128}, {128, 256, 128, 256} };

    for (int li = 0; li < 4; ++li) {
        const L& ly = layers[li];
        const unsigned short* Ahp;
        const unsigned short* Alp;
        int strideA;
        if (li == 0) { Ahp = x1h; Alp = x1l; strideA = 32; }
        else {
            int po = layers[li - 1].hoff;
            Ahp = hh + po; Alp = hl + po; strideA = 512;
            sqnorm_hl<<<M_ROWS / 4, 256, 0, stream>>>(Ahp, Alp, ly.D, sq);
        }

        if (li == 0)
            knn_mfma<32><<<dim3(N_PTS / 128, BATCH), 256, 0, stream>>>(Ahp, Alp, strideA, sq, idx);
        else if (ly.D == 64)
            knn_mfma<64><<<dim3(N_PTS / 128, BATCH), 256, 0, stream>>>(Ahp, Alp, strideA, sq, idx);
        else
            knn_mfma<128><<<dim3(N_PTS / 128, BATCH), 256, 0, stream>>>(Ahp, Alp, strideA, sq, idx);

        repack_edge_split<<<(2 * ly.Co * ly.KP + 255) / 256, 256, 0, stream>>>(
            W[li], ly.Co, ly.D, ly.KP, Wh, Wl);
        fgemm<<<dim3((2 * ly.Co) / 128, M_ROWS / 128), 256, 0, stream>>>(
            Ahp, Alp, strideA, ly.KP, Wh, Wl, 2 * ly.Co, zc2, 0, nullptr, nullptr);
        pool_kernel<<<dim3(N_PTS, BATCH), ly.Co, 0, stream>>>(
            zc2, ly.Co, idx, gg[li], bb[li], hh, hl, ly.hoff);
    }

    // layer 5
    repack_w5_split<<<(512 * 512 + 255) / 256, 256, 0, stream>>>(W[4], Wh, Wl);
    fgemm<<<dim3(4, M_ROWS / 128), 256, 0, stream>>>(
        hh, hl, 512, 512, Wh, Wl, 512, zc2, 1, gg[4], bb[4]);

    reduce_partial<<<dim3(16, BATCH), 512, 0, stream>>>(zc2, pmx, psm);
    reduce_final<<<(BATCH * 512 + 255) / 256, 256, 0, stream>>>(pmx, psm, outp);
}

// Round 5
// 1585.380 us; speedup vs baseline: 5.7706x; 2.8894x over previous
//
#include <hip/hip_runtime.h>
#include <math.h>

#define BATCH 8
#define N_PTS 4096
#define KNN 20
#define EPS_BN 1e-5f
#define SLOPE 0.2f
#define M_ROWS (BATCH * N_PTS)

typedef __attribute__((ext_vector_type(8))) short short8;     // bf16 x8 (4 VGPR)
typedef __attribute__((ext_vector_type(4))) float float4v;    // fp32 x4 acc

__device__ __forceinline__ unsigned short f2bf(float f) {
    unsigned u = __float_as_uint(f);
    unsigned r = (u + 0x7FFFu + ((u >> 16) & 1u)) >> 16;
    return (unsigned short)r;
}
__device__ __forceinline__ float bf2f(unsigned short h) {
    return __uint_as_float((unsigned)h << 16);
}

// ---------------------------------------------------------------------------
// x (B,3,N) fp32 -> x1h/x1l (M,32) bf16 split (zero-padded), + sq norms
__global__ void convert_x1(const float* __restrict__ x,
                           unsigned short* __restrict__ xh, unsigned short* __restrict__ xl,
                           float* __restrict__ sq) {
    int i = blockIdx.x * blockDim.x + threadIdx.x;
    if (i >= M_ROWS) return;
    int b = i / N_PTS, n = i % N_PTS;
    float v[3], s = 0.f;
    #pragma unroll
    for (int d = 0; d < 3; ++d) {
        v[d] = x[((size_t)b * 3 + d) * N_PTS + n];
        s += v[d] * v[d];
    }
    sq[i] = s;
    #pragma unroll
    for (int d = 0; d < 32; ++d) {
        float f = (d < 3) ? v[d] : 0.f;
        unsigned short h = f2bf(f);
        xh[(size_t)i * 32 + d] = h;
        xl[(size_t)i * 32 + d] = f2bf(f - bf2f(h));
    }
}

// sq norms from bf16 hi/lo feature rows (stride 512)
__global__ void sqnorm_hl(const unsigned short* __restrict__ hh,
                          const unsigned short* __restrict__ hl,
                          int D, float* __restrict__ sq) {
    int w = threadIdx.x >> 6, lane = threadIdx.x & 63;
    int row = blockIdx.x * 4 + w;
    if (row >= M_ROWS) return;
    const unsigned short* ph = hh + (size_t)row * 512;
    const unsigned short* pl = hl + (size_t)row * 512;
    float s = 0.f;
    for (int d = lane; d < D; d += 64) {
        float v = bf2f(ph[d]) + bf2f(pl[d]);
        s += v * v;
    }
    #pragma unroll
    for (int off = 32; off > 0; off >>= 1) s += __shfl_down(s, off, 64);
    if (lane == 0) sq[row] = s;
}

// ---------------------------------------------------------------------------
// weight repacks -> bf16 hi/lo, B-operand layout [C][KP] (k contiguous)
__global__ void repack_edge_split(const float* __restrict__ W, int Co, int D, int KP,
                                  unsigned short* __restrict__ Wh, unsigned short* __restrict__ Wl) {
    int i = blockIdx.x * blockDim.x + threadIdx.x;
    int tot = 2 * Co * KP;
    if (i >= tot) return;
    int r = i / KP, d = i % KP;
    float v = 0.f;
    if (d < D) v = (r < Co) ? W[(size_t)r * 2 * D + d] : W[(size_t)(r - Co) * 2 * D + D + d];
    unsigned short h = f2bf(v);
    Wh[i] = h; Wl[i] = f2bf(v - bf2f(h));
}

__global__ void repack_w5_split(const float* __restrict__ W,
                                unsigned short* __restrict__ Wh, unsigned short* __restrict__ Wl) {
    int i = blockIdx.x * blockDim.x + threadIdx.x;
    if (i >= 512 * 512) return;
    float v = W[i];
    unsigned short h = f2bf(v);
    Wh[i] = h; Wl[i] = f2bf(v - bf2f(h));
}

// ---------------------------------------------------------------------------
// MFMA KNN v5: 64 rows/block, exact fp32 (val,idx) streaming top-20 with
// mask-batched insertion. grid: (N/64, B), block 256.
// Wave w computes rows [w*16, w*16+16) x 64 cols; selection thread (r, t)
// scans candidates col == t (mod 4), ascending.
template<int DPAD>
__launch_bounds__(256, 3)
__global__ void knn_mfma(const unsigned short* __restrict__ Xh,
                         const unsigned short* __restrict__ Xl,
                         int strideX,
                         const float* __restrict__ sq, int* __restrict__ idxout) {
    constexpr int KS  = DPAD / 32;
    constexpr int BST = DPAD + 8;             // LDS row stride (ushorts)
    constexpr int C8  = DPAD / 8;
    constexpr int SB  = 64 * BST;             // ushorts per stage buffer
    constexpr size_t STAGE = (size_t)2 * SB * 2 + (size_t)64 * 65 * 4 + 64 * 4;
    constexpr size_t MERGE = (size_t)64 * 61 * 4 * 2;
    constexpr size_t POOL  = STAGE > MERGE ? STAGE : MERGE;
    __shared__ __align__(16) char smem[POOL];
    unsigned short* BhS = (unsigned short*)smem;
    unsigned short* BlS = BhS + SB;
    float* Sf  = (float*)(smem + (size_t)2 * SB * 2);   // [64 rows][65] scores
    float* sqs = Sf + 64 * 65;
    float*    kb = (float*)smem;                        // merge: [64][61] vals
    unsigned* ib = (unsigned*)(kb + 64 * 61);           //        [64][61] idx

    const int b = blockIdx.y;
    const int row0 = blockIdx.x * 64;
    const int tid = threadIdx.x;
    const int w = tid >> 6, lane = tid & 63;
    const int n = lane & 15, q = lane >> 4;
    const int r = tid & 63, t = tid >> 6;     // selection row / col-phase

    const unsigned short* Xhb = Xh + (size_t)b * N_PTS * strideX;
    const unsigned short* Xlb = Xl + (size_t)b * N_PTS * strideX;
    const float* sqb = sq + (size_t)b * N_PTS;

    // A fragments (registers): wave w rows w*16 + n
    short8 ah[KS], al[KS];
    #pragma unroll
    for (int ks = 0; ks < KS; ++ks) {
        size_t o = (size_t)(row0 + w * 16 + n) * strideX + ks * 32 + q * 8;
        ah[ks] = *(const short8*)(Xhb + o);
        al[ks] = *(const short8*)(Xlb + o);
    }

    // per-thread top-20: exact fp32 score + full index, ascending by (val,idx)
    float fv[KNN]; int fi[KNN];
    #pragma unroll
    for (int p = 0; p < KNN; ++p) { fv[p] = INFINITY; fi[p] = 0x7FFFFFFF; }

    for (int c0 = 0; c0 < N_PTS; c0 += 64) {
        __syncthreads();
        // stage B tile (64 cols x DPAD, hi+lo)
        for (int tt = tid; tt < 64 * C8; tt += 256) {
            int rr = tt / C8, c8 = tt % C8;
            size_t o = (size_t)(c0 + rr) * strideX + c8 * 8;
            *(short8*)&BhS[rr * BST + c8 * 8] = *(const short8*)(Xhb + o);
            *(short8*)&BlS[rr * BST + c8 * 8] = *(const short8*)(Xlb + o);
        }
        if (tid < 64) sqs[tid] = sqb[c0 + tid];
        __syncthreads();

        float4v acc[4];
        #pragma unroll
        for (int ct = 0; ct < 4; ++ct) acc[ct] = (float4v){0.f, 0.f, 0.f, 0.f};

        #pragma unroll
        for (int ks = 0; ks < KS; ++ks) {
            #pragma unroll
            for (int ct = 0; ct < 4; ++ct) {
                short8 bh = *(const short8*)&BhS[(ct * 16 + n) * BST + ks * 32 + q * 8];
                short8 bl = *(const short8*)&BlS[(ct * 16 + n) * BST + ks * 32 + q * 8];
                acc[ct] = __builtin_amdgcn_mfma_f32_16x16x32_bf16(ah[ks], bh, acc[ct], 0, 0, 0);
                acc[ct] = __builtin_amdgcn_mfma_f32_16x16x32_bf16(al[ks], bh, acc[ct], 0, 0, 0);
                acc[ct] = __builtin_amdgcn_mfma_f32_16x16x32_bf16(ah[ks], bl, acc[ct], 0, 0, 0);
            }
        }

        // epilogue: Sf[row][ (col&3)*16 + (col>>2) ] = sq[col] - 2*dot
        // (phase-major within row so each selection thread's 16 candidates
        //  are contiguous; stride 65 keeps accesses <=2-way on banks)
        #pragma unroll
        for (int ct = 0; ct < 4; ++ct) {
            int lc = ct * 16 + n;
            int pos = (n & 3) * 16 + ct * 4 + (n >> 2);   // (lc&3)*16 + (lc>>2)
            float sc = sqs[lc];
            #pragma unroll
            for (int e = 0; e < 4; ++e)
                Sf[(w * 16 + q * 4 + e) * 65 + pos] = sc - 2.f * acc[ct][e];
        }
        __syncthreads();

        // selection: scan 16 candidates (ascending jj == ascending col),
        // build qualify mask, then batch-insert (wave executes the cascade
        // only max-over-lanes(popcount) times).
        const int sbase = r * 65 + t * 16;
        unsigned mask = 0;
        #pragma unroll
        for (int jj = 0; jj < 16; ++jj) {
            float v = Sf[sbase + jj];
            if (v < fv[KNN - 1]) mask |= (1u << jj);
        }
        while (mask) {
            int jj = __ffs(mask) - 1;
            mask &= mask - 1;
            float v = Sf[sbase + jj];
            if (v < fv[KNN - 1]) {     // strict: earlier (lower idx) wins ties
                fv[KNN - 1] = v;
                fi[KNN - 1] = c0 + (jj << 2) + t;
                #pragma unroll
                for (int p = KNN - 1; p > 0; --p) {
                    float va = fv[p - 1], vb = fv[p];
                    int   ia = fi[p - 1], ic = fi[p];
                    bool sw = vb < va;
                    fv[p - 1] = sw ? vb : va; fv[p] = sw ? va : vb;
                    fi[p - 1] = sw ? ic : ia; fi[p] = sw ? ia : ic;
                }
            }
        }
    }
    __syncthreads();

    // dump slices t=1..3, lex-merge on threads 0..63
    if (t > 0) {
        #pragma unroll
        for (int p = 0; p < KNN; ++p) {
            kb[r * 61 + (t - 1) * KNN + p] = fv[p];
            ib[r * 61 + (t - 1) * KNN + p] = (unsigned)fi[p];
        }
    }
    __syncthreads();
    if (tid < 64) {
        #pragma unroll 1
        for (int qq = 0; qq < 3 * KNN; ++qq) {
            float    v  = kb[tid * 61 + qq];
            unsigned ii = ib[tid * 61 + qq];
            bool ins = (v < fv[KNN - 1]) ||
                       (v == fv[KNN - 1] && (int)ii < fi[KNN - 1]);
            if (ins) {
                fv[KNN - 1] = v; fi[KNN - 1] = (int)ii;
                #pragma unroll
                for (int p = KNN - 1; p > 0; --p) {
                    float va = fv[p - 1], vb = fv[p];
                    int   ia = fi[p - 1], ic = fi[p];
                    bool sw = (vb < va) || (vb == va && ic < ia);
                    fv[p - 1] = sw ? vb : va; fv[p] = sw ? va : vb;
                    fi[p - 1] = sw ? ic : ia; fi[p] = sw ? ia : ic;
                }
            }
        }
        int* op = idxout + ((size_t)(b * N_PTS + row0 + tid)) * KNN;
        #pragma unroll
        for (int p = 0; p < KNN; ++p) op[p] = fi[p];
    }
}

// ---------------------------------------------------------------------------
// MFMA feature GEMM: out[m,c] = sum_k A[m,k]*W[c,k], bf16 hi/lo 3-pass.
__launch_bounds__(256)
__global__ void fgemm(const unsigned short* __restrict__ Ah, const unsigned short* __restrict__ Al,
                      int strideA, int K,
                      const unsigned short* __restrict__ Wh, const unsigned short* __restrict__ Wl,
                      int C, float* __restrict__ out, int fuse_bn,
                      const float* __restrict__ g, const float* __restrict__ beta) {
    __shared__ unsigned short AhS[128 * 40];
    __shared__ unsigned short AlS[128 * 40];
    __shared__ unsigned short BhS[128 * 40];
    __shared__ unsigned short BlS[128 * 40];

    const int c0 = blockIdx.x * 128;
    const int m0 = blockIdx.y * 128;
    const int tid = threadIdx.x;
    const int w = tid >> 6, lane = tid & 63;
    const int n = lane & 15, q = lane >> 4;

    float4v acc[2][8];
    #pragma unroll
    for (int rt = 0; rt < 2; ++rt)
        #pragma unroll
        for (int ct = 0; ct < 8; ++ct) acc[rt][ct] = (float4v){0.f, 0.f, 0.f, 0.f};

    for (int kk = 0; kk < K; kk += 32) {
        __syncthreads();
        for (int tt = tid; tt < 512; tt += 256) {
            int rr = tt >> 2, c8 = tt & 3;
            size_t oa = (size_t)(m0 + rr) * strideA + kk + c8 * 8;
            *(short8*)&AhS[rr * 40 + c8 * 8] = *(const short8*)(Ah + oa);
            *(short8*)&AlS[rr * 40 + c8 * 8] = *(const short8*)(Al + oa);
            size_t ob = (size_t)(c0 + rr) * K + kk + c8 * 8;
            *(short8*)&BhS[rr * 40 + c8 * 8] = *(const short8*)(Wh + ob);
            *(short8*)&BlS[rr * 40 + c8 * 8] = *(const short8*)(Wl + ob);
        }
        __syncthreads();

        short8 af[2][2];
        #pragma unroll
        for (int rt = 0; rt < 2; ++rt) {
            af[rt][0] = *(const short8*)&AhS[(w * 32 + rt * 16 + n) * 40 + q * 8];
            af[rt][1] = *(const short8*)&AlS[(w * 32 + rt * 16 + n) * 40 + q * 8];
        }
        #pragma unroll
        for (int ct = 0; ct < 8; ++ct) {
            short8 bh = *(const short8*)&BhS[(ct * 16 + n) * 40 + q * 8];
            short8 bl = *(const short8*)&BlS[(ct * 16 + n) * 40 + q * 8];
            #pragma unroll
            for (int rt = 0; rt < 2; ++rt) {
                acc[rt][ct] = __builtin_amdgcn_mfma_f32_16x16x32_bf16(af[rt][0], bh, acc[rt][ct], 0, 0, 0);
                acc[rt][ct] = __builtin_amdgcn_mfma_f32_16x16x32_bf16(af[rt][1], bh, acc[rt][ct], 0, 0, 0);
                acc[rt][ct] = __builtin_amdgcn_mfma_f32_16x16x32_bf16(af[rt][0], bl, acc[rt][ct], 0, 0, 0);
            }
        }
    }

    #pragma unroll
    for (int rt = 0; rt < 2; ++rt)
        #pragma unroll
        for (int ct = 0; ct < 8; ++ct) {
            int c = c0 + ct * 16 + n;
            float sc = 1.f, bt = 0.f;
            if (fuse_bn) { sc = g[c] / sqrtf(1.f + EPS_BN); bt = beta[c]; }
            #pragma unroll
            for (int e = 0; e < 4; ++e) {
                int m = m0 + w * 32 + rt * 16 + q * 4 + e;
                float v = acc[rt][ct][e];
                if (fuse_bn) { v = v * sc + bt; v = (v >= 0.f) ? v : SLOPE * v; }
                out[(size_t)m * C + c] = v;
            }
        }
}

// ---------------------------------------------------------------------------
// EdgeConv max-pool epilogue -> bf16 hi/lo feature rows
__global__ void pool_kernel(const float* __restrict__ zc2, int Co,
                            const int* __restrict__ idx,
                            const float* __restrict__ g, const float* __restrict__ beta,
                            unsigned short* __restrict__ hh, unsigned short* __restrict__ hl,
                            int hoff) {
    int n = blockIdx.x, b = blockIdx.y;
    int o = threadIdx.x;
    size_t bn = (size_t)b * N_PTS + n;
    const int* ip = idx + bn * KNN;
    float zn   = zc2[bn * (size_t)(2 * Co) + o];
    float base = zc2[bn * (size_t)(2 * Co) + Co + o] - zn;
    float m = -INFINITY;
    #pragma unroll
    for (int j = 0; j < KNN; ++j) {
        size_t rr = (size_t)b * N_PTS + ip[j];
        m = fmaxf(m, zc2[rr * (size_t)(2 * Co) + o]);
    }
    float y = m + base;
    float sc = g[o] / sqrtf(1.f + EPS_BN);
    y = y * sc + beta[o];
    y = (y >= 0.f) ? y : SLOPE * y;
    unsigned short h = f2bf(y);
    hh[bn * 512 + hoff + o] = h;
    hl[bn * 512 + hoff + o] = f2bf(y - bf2f(h));
}

// ---------------------------------------------------------------------------
// final global max/mean over N: two-stage
__global__ void reduce_partial(const float* __restrict__ y5,
                               float* __restrict__ pmax, float* __restrict__ psum) {
    int chunk = blockIdx.x, b = blockIdx.y, c = threadIdx.x;
    float mx = -INFINITY, sm = 0.f;
    for (int qq = 0; qq < 256; ++qq) {
        int n = chunk * 256 + qq;
        float v = y5[((size_t)b * N_PTS + n) * 512 + c];
        mx = fmaxf(mx, v);
        sm += v;
    }
    pmax[((size_t)b * 16 + chunk) * 512 + c] = mx;
    psum[((size_t)b * 16 + chunk) * 512 + c] = sm;
}

__global__ void reduce_final(const float* __restrict__ pmax,
                             const float* __restrict__ psum,
                             float* __restrict__ out) {
    int i = blockIdx.x * blockDim.x + threadIdx.x;
    if (i >= BATCH * 512) return;
    int b = i / 512, c = i % 512;
    float mx = -INFINITY, sm = 0.f;
    for (int qq = 0; qq < 16; ++qq) {
        mx = fmaxf(mx, pmax[((size_t)b * 16 + qq) * 512 + c]);
        sm += psum[((size_t)b * 16 + qq) * 512 + c];
    }
    out[(size_t)b * 1024 + c] = mx;
    out[(size_t)b * 1024 + 512 + c] = sm * (1.f / 4096.f);
}

// ---------------------------------------------------------------------------
extern "C" void kernel_launch(void* const* d_in, const int* in_sizes, int n_in,
                              void* d_out, int out_size, void* d_ws, size_t ws_size,
                              hipStream_t stream) {
    const float* x = (const float*)d_in[0];
    const float* W[5], *gg[5], *bb[5];
    for (int i = 0; i < 5; ++i) {
        W[i]  = (const float*)d_in[2 + 3 * i];
        gg[i] = (const float*)d_in[3 + 3 * i];
        bb[i] = (const float*)d_in[4 + 3 * i];
    }
    float* outp = (float*)d_out;

    char* wsb = (char*)d_ws;
    size_t off = 0;
    unsigned short* x1h = (unsigned short*)(wsb + off); off += (size_t)M_ROWS * 32 * 2;
    unsigned short* x1l = (unsigned short*)(wsb + off); off += (size_t)M_ROWS * 32 * 2;
    float* sq = (float*)(wsb + off); off += (size_t)M_ROWS * 4;
    int*   idx = (int*)(wsb + off); off += (size_t)M_ROWS * KNN * 4;
    unsigned short* Wh = (unsigned short*)(wsb + off); off += (size_t)512 * 512 * 2;
    unsigned short* Wl = (unsigned short*)(wsb + off); off += (size_t)512 * 512 * 2;
    unsigned short* hh = (unsigned short*)(wsb + off); off += (size_t)M_ROWS * 512 * 2;
    unsigned short* hl = (unsigned short*)(wsb + off); off += (size_t)M_ROWS * 512 * 2;
    float* zc2 = (float*)(wsb + off); off += (size_t)M_ROWS * 512 * 4;
    float* pmx = (float*)(wsb + off); off += (size_t)BATCH * 16 * 512 * 4;
    float* psm = (float*)(wsb + off); off += (size_t)BATCH * 16 * 512 * 4;
    (void)ws_size; (void)in_sizes; (void)n_in; (void)out_size;

    convert_x1<<<(M_ROWS + 255) / 256, 256, 0, stream>>>(x, x1h, x1l, sq);

    struct L { int D, Co, KP, hoff; };
    const L layers[4] = { {3, 64, 32, 0}, {64, 64, 64, 64}, {64, 128, 64, 128}, {128, 256, 128, 256} };

    for (int li = 0; li < 4; ++li) {
        const L& ly = layers[li];
        const unsigned short* Ahp;
        const unsigned short* Alp;
        int strideA;
        if (li == 0) { Ahp = x1h; Alp = x1l; strideA = 32; }
        else {
            int po = layers[li - 1].hoff;
            Ahp = hh + po; Alp = hl + po; strideA = 512;
            sqnorm_hl<<<M_ROWS / 4, 256, 0, stream>>>(Ahp, Alp, ly.D, sq);
        }

        if (li == 0)
            knn_mfma<32><<<dim3(N_PTS / 64, BATCH), 256, 0, stream>>>(Ahp, Alp, strideA, sq, idx);
        else if (ly.D == 64)
            knn_mfma<64><<<dim3(N_PTS / 64, BATCH), 256, 0, stream>>>(Ahp, Alp, strideA, sq, idx);
        else
            knn_mfma<128><<<dim3(N_PTS / 64, BATCH), 256, 0, stream>>>(Ahp, Alp, strideA, sq, idx);

        repack_edge_split<<<(2 * ly.Co * ly.KP + 255) / 256, 256, 0, stream>>>(
            W[li], ly.Co, ly.D, ly.KP, Wh, Wl);
        fgemm<<<dim3((2 * ly.Co) / 128, M_ROWS / 128), 256, 0, stream>>>(
            Ahp, Alp, strideA, ly.KP, Wh, Wl, 2 * ly.Co, zc2, 0, nullptr, nullptr);
        pool_kernel<<<dim3(N_PTS, BATCH), ly.Co, 0, stream>>>(
            zc2, ly.Co, idx, gg[li], bb[li], hh, hl, ly.hoff);
    }

    // layer 5
    repack_w5_split<<<(512 * 512 + 255) / 256, 256, 0, stream>>>(W[4], Wh, Wl);
    fgemm<<<dim3(4, M_ROWS / 128), 256, 0, stream>>>(
        hh, hl, 512, 512, Wh, Wl, 512, zc2, 1, gg[4], bb[4]);

    reduce_partial<<<dim3(16, BATCH), 512, 0, stream>>>(zc2, pmx, psm);
    reduce_final<<<(BATCH * 512 + 255) / 256, 256, 0, stream>>>(pmx, psm, outp);
}

// Round 6
// 1459.361 us; speedup vs baseline: 6.2690x; 1.0864x over previous
//
#include <hip/hip_runtime.h>
#include <math.h>

#define BATCH 8
#define N_PTS 4096
#define KNN 20
#define EPS_BN 1e-5f
#define SLOPE 0.2f
#define M_ROWS (BATCH * N_PTS)

typedef __attribute__((ext_vector_type(8))) short short8;      // bf16 x8 (4 VGPR)
typedef __attribute__((ext_vector_type(4))) float float4v;     // fp32 x4 acc
typedef __attribute__((ext_vector_type(16))) float float16v;   // fp32 x16 acc

__device__ __forceinline__ unsigned short f2bf(float f) {
    unsigned u = __float_as_uint(f);
    unsigned r = (u + 0x7FFFu + ((u >> 16) & 1u)) >> 16;
    return (unsigned short)r;
}
__device__ __forceinline__ float bf2f(unsigned short h) {
    return __uint_as_float((unsigned)h << 16);
}

// ---------------------------------------------------------------------------
// x (B,3,N) fp32 -> x1h/x1l (M,32) bf16 split (zero-padded), + sq norms
__global__ void convert_x1(const float* __restrict__ x,
                           unsigned short* __restrict__ xh, unsigned short* __restrict__ xl,
                           float* __restrict__ sq) {
    int i = blockIdx.x * blockDim.x + threadIdx.x;
    if (i >= M_ROWS) return;
    int b = i / N_PTS, n = i % N_PTS;
    float v[3], s = 0.f;
    #pragma unroll
    for (int d = 0; d < 3; ++d) {
        v[d] = x[((size_t)b * 3 + d) * N_PTS + n];
        s += v[d] * v[d];
    }
    sq[i] = s;
    #pragma unroll
    for (int d = 0; d < 32; ++d) {
        float f = (d < 3) ? v[d] : 0.f;
        unsigned short h = f2bf(f);
        xh[(size_t)i * 32 + d] = h;
        xl[(size_t)i * 32 + d] = f2bf(f - bf2f(h));
    }
}

// sq norms from bf16 hi/lo feature rows (stride 512)
__global__ void sqnorm_hl(const unsigned short* __restrict__ hh,
                          const unsigned short* __restrict__ hl,
                          int D, float* __restrict__ sq) {
    int w = threadIdx.x >> 6, lane = threadIdx.x & 63;
    int row = blockIdx.x * 4 + w;
    if (row >= M_ROWS) return;
    const unsigned short* ph = hh + (size_t)row * 512;
    const unsigned short* pl = hl + (size_t)row * 512;
    float s = 0.f;
    for (int d = lane; d < D; d += 64) {
        float v = bf2f(ph[d]) + bf2f(pl[d]);
        s += v * v;
    }
    #pragma unroll
    for (int off = 32; off > 0; off >>= 1) s += __shfl_down(s, off, 64);
    if (lane == 0) sq[row] = s;
}

// ---------------------------------------------------------------------------
// weight repacks -> bf16 hi/lo, B-operand layout [C][KP] (k contiguous)
__global__ void repack_edge_split(const float* __restrict__ W, int Co, int D, int KP,
                                  unsigned short* __restrict__ Wh, unsigned short* __restrict__ Wl) {
    int i = blockIdx.x * blockDim.x + threadIdx.x;
    int tot = 2 * Co * KP;
    if (i >= tot) return;
    int r = i / KP, d = i % KP;
    float v = 0.f;
    if (d < D) v = (r < Co) ? W[(size_t)r * 2 * D + d] : W[(size_t)(r - Co) * 2 * D + D + d];
    unsigned short h = f2bf(v);
    Wh[i] = h; Wl[i] = f2bf(v - bf2f(h));
}

__global__ void repack_w5_split(const float* __restrict__ W,
                                unsigned short* __restrict__ Wh, unsigned short* __restrict__ Wl) {
    int i = blockIdx.x * blockDim.x + threadIdx.x;
    if (i >= 512 * 512) return;
    float v = W[i];
    unsigned short h = f2bf(v);
    Wh[i] = h; Wl[i] = f2bf(v - bf2f(h));
}

// ---------------------------------------------------------------------------
// MFMA KNN v6: 64 rows/block, 32x32x16 MFMA (one 32x32 tile per wave),
// XOR-swizzled pad-free B staging, exact fp32 (val,idx) streaming top-20.
// grid: (N/64, B), block 256.
template<int DPAD>
__launch_bounds__(256, 2)
__global__ void knn_mfma(const unsigned short* __restrict__ Xh,
                         const unsigned short* __restrict__ Xl,
                         int strideX,
                         const float* __restrict__ sq, int* __restrict__ idxout) {
    constexpr int KS16 = DPAD / 16;           // mfma k-steps (K=16)
    constexpr int C8   = DPAD / 8;            // 16B chunks per col
    constexpr int XK   = (C8 - 1) < 7 ? (C8 - 1) : 7;   // xor swizzle key mask
    constexpr int SB   = 64 * DPAD;           // ushorts per stage buffer
    constexpr size_t STAGE = (size_t)2 * SB * 2 + (size_t)64 * 65 * 4 + 64 * 4;
    constexpr size_t MERGE = (size_t)64 * 61 * 4 * 2;
    constexpr size_t POOL  = STAGE > MERGE ? STAGE : MERGE;
    __shared__ __align__(16) char smem[POOL];
    unsigned short* BhS = (unsigned short*)smem;
    unsigned short* BlS = BhS + SB;
    float* Sf  = (float*)(smem + (size_t)2 * SB * 2);   // [64 rows][65] scores
    float* sqs = Sf + 64 * 65;
    float*    kb = (float*)smem;                        // merge: [64][61] vals
    unsigned* ib = (unsigned*)(kb + 64 * 61);           //        [64][61] idx

    const int b = blockIdx.y;
    const int row0 = blockIdx.x * 64;
    const int tid = threadIdx.x;
    const int w = tid >> 6, lane = tid & 63;
    const int l31 = lane & 31, lh = lane >> 5;
    const int r = tid & 63, t = tid >> 6;     // selection row / col-phase
    const int rbase = (w & 1) * 32;           // wave's row half
    const int cb32  = (w >> 1) * 32;          // wave's col half

    const unsigned short* Xhb = Xh + (size_t)b * N_PTS * strideX;
    const unsigned short* Xlb = Xl + (size_t)b * N_PTS * strideX;
    const float* sqb = sq + (size_t)b * N_PTS;

    // A fragments (registers): rows row0+rbase+l31, k = ks*16 + lh*8 + j
    short8 ah[KS16], al[KS16];
    #pragma unroll
    for (int ks = 0; ks < KS16; ++ks) {
        size_t o = (size_t)(row0 + rbase + l31) * strideX + ks * 16 + lh * 8;
        ah[ks] = *(const short8*)(Xhb + o);
        al[ks] = *(const short8*)(Xlb + o);
    }

    // per-thread top-20: exact fp32 score + full index, ascending by (val,idx)
    float fv[KNN]; int fi[KNN];
    #pragma unroll
    for (int p = 0; p < KNN; ++p) { fv[p] = INFINITY; fi[p] = 0x7FFFFFFF; }

    for (int c0 = 0; c0 < N_PTS; c0 += 64) {
        __syncthreads();
        // stage B tile: slot tt (linear -> conflict-free stores) holds
        // chunk (col = tt/C8, kc_global = (tt%C8) ^ (col&XK))
        #pragma unroll
        for (int it = 0; it < (64 * C8 + 255) / 256; ++it) {
            int tt = tid + it * 256;
            int col = tt / C8, kcs = tt % C8;
            int kcg = kcs ^ (col & XK);
            size_t o = (size_t)(c0 + col) * strideX + kcg * 8;
            *(short8*)&BhS[tt * 8] = *(const short8*)(Xhb + o);
            *(short8*)&BlS[tt * 8] = *(const short8*)(Xlb + o);
        }
        if (tid < 64) sqs[tid] = sqb[c0 + tid];
        __syncthreads();

        float16v acc = {};

        const int colL = cb32 + l31;
        const int cbase_us = colL * DPAD;
        #pragma unroll
        for (int ks = 0; ks < KS16; ++ks) {
            int ch = ((ks * 2 + lh) ^ (colL & XK)) * 8;
            short8 bh = *(const short8*)&BhS[cbase_us + ch];
            short8 bl = *(const short8*)&BlS[cbase_us + ch];
            acc = __builtin_amdgcn_mfma_f32_32x32x16_bf16(ah[ks], bh, acc, 0, 0, 0);
            acc = __builtin_amdgcn_mfma_f32_32x32x16_bf16(al[ks], bh, acc, 0, 0, 0);
            acc = __builtin_amdgcn_mfma_f32_32x32x16_bf16(ah[ks], bl, acc, 0, 0, 0);
        }

        // epilogue: Sf[row][(col&3)*16 + (col>>2)] = sq[col] - 2*dot
        // C layout (32x32): col = lane&31, row = (reg&3) + 8*(reg>>2) + 4*(lane>>5)
        {
            float sc = sqs[colL];
            int pos = (colL & 3) * 16 + (colL >> 2);
            #pragma unroll
            for (int reg = 0; reg < 16; ++reg) {
                int rowL = rbase + (reg & 3) + 8 * (reg >> 2) + 4 * lh;
                Sf[rowL * 65 + pos] = sc - 2.f * acc[reg];
            }
        }
        __syncthreads();

        // selection: thread (r,t) scans candidates col = c0 + 4*jj + t
        const int sbase = r * 65 + t * 16;
        unsigned mask = 0;
        #pragma unroll
        for (int jj = 0; jj < 16; ++jj) {
            float v = Sf[sbase + jj];
            if (v < fv[KNN - 1]) mask |= (1u << jj);
        }
        while (mask) {
            int jj = __ffs(mask) - 1;
            mask &= mask - 1;
            float v = Sf[sbase + jj];
            if (v < fv[KNN - 1]) {     // strict: earlier (lower idx) wins ties
                fv[KNN - 1] = v;
                fi[KNN - 1] = c0 + (jj << 2) + t;
                #pragma unroll
                for (int p = KNN - 1; p > 0; --p) {
                    float va = fv[p - 1], vb = fv[p];
                    int   ia = fi[p - 1], ic = fi[p];
                    bool sw = vb < va;
                    fv[p - 1] = sw ? vb : va; fv[p] = sw ? va : vb;
                    fi[p - 1] = sw ? ic : ia; fi[p] = sw ? ia : ic;
                }
            }
        }
    }
    __syncthreads();

    // dump slices t=1..3, lex-merge on threads 0..63
    if (t > 0) {
        #pragma unroll
        for (int p = 0; p < KNN; ++p) {
            kb[r * 61 + (t - 1) * KNN + p] = fv[p];
            ib[r * 61 + (t - 1) * KNN + p] = (unsigned)fi[p];
        }
    }
    __syncthreads();
    if (tid < 64) {
        #pragma unroll 1
        for (int qq = 0; qq < 3 * KNN; ++qq) {
            float    v  = kb[tid * 61 + qq];
            unsigned ii = ib[tid * 61 + qq];
            bool ins = (v < fv[KNN - 1]) ||
                       (v == fv[KNN - 1] && (int)ii < fi[KNN - 1]);
            if (ins) {
                fv[KNN - 1] = v; fi[KNN - 1] = (int)ii;
                #pragma unroll
                for (int p = KNN - 1; p > 0; --p) {
                    float va = fv[p - 1], vb = fv[p];
                    int   ia = fi[p - 1], ic = fi[p];
                    bool sw = (vb < va) || (vb == va && ic < ia);
                    fv[p - 1] = sw ? vb : va; fv[p] = sw ? va : vb;
                    fi[p - 1] = sw ? ic : ia; fi[p] = sw ? ia : ic;
                }
            }
        }
        int* op = idxout + ((size_t)(b * N_PTS + row0 + tid)) * KNN;
        #pragma unroll
        for (int p = 0; p < KNN; ++p) op[p] = fi[p];
    }
}

// ---------------------------------------------------------------------------
// MFMA feature GEMM: out[m,c] = sum_k A[m,k]*W[c,k], bf16 hi/lo 3-pass.
__launch_bounds__(256)
__global__ void fgemm(const unsigned short* __restrict__ Ah, const unsigned short* __restrict__ Al,
                      int strideA, int K,
                      const unsigned short* __restrict__ Wh, const unsigned short* __restrict__ Wl,
                      int C, float* __restrict__ out, int fuse_bn,
                      const float* __restrict__ g, const float* __restrict__ beta) {
    __shared__ unsigned short AhS[128 * 40];
    __shared__ unsigned short AlS[128 * 40];
    __shared__ unsigned short BhS[128 * 40];
    __shared__ unsigned short BlS[128 * 40];

    const int c0 = blockIdx.x * 128;
    const int m0 = blockIdx.y * 128;
    const int tid = threadIdx.x;
    const int w = tid >> 6, lane = tid & 63;
    const int n = lane & 15, q = lane >> 4;

    float4v acc[2][8];
    #pragma unroll
    for (int rt = 0; rt < 2; ++rt)
        #pragma unroll
        for (int ct = 0; ct < 8; ++ct) acc[rt][ct] = (float4v){0.f, 0.f, 0.f, 0.f};

    for (int kk = 0; kk < K; kk += 32) {
        __syncthreads();
        for (int tt = tid; tt < 512; tt += 256) {
            int rr = tt >> 2, c8 = tt & 3;
            size_t oa = (size_t)(m0 + rr) * strideA + kk + c8 * 8;
            *(short8*)&AhS[rr * 40 + c8 * 8] = *(const short8*)(Ah + oa);
            *(short8*)&AlS[rr * 40 + c8 * 8] = *(const short8*)(Al + oa);
            size_t ob = (size_t)(c0 + rr) * K + kk + c8 * 8;
            *(short8*)&BhS[rr * 40 + c8 * 8] = *(const short8*)(Wh + ob);
            *(short8*)&BlS[rr * 40 + c8 * 8] = *(const short8*)(Wl + ob);
        }
        __syncthreads();

        short8 af[2][2];
        #pragma unroll
        for (int rt = 0; rt < 2; ++rt) {
            af[rt][0] = *(const short8*)&AhS[(w * 32 + rt * 16 + n) * 40 + q * 8];
            af[rt][1] = *(const short8*)&AlS[(w * 32 + rt * 16 + n) * 40 + q * 8];
        }
        #pragma unroll
        for (int ct = 0; ct < 8; ++ct) {
            short8 bh = *(const short8*)&BhS[(ct * 16 + n) * 40 + q * 8];
            short8 bl = *(const short8*)&BlS[(ct * 16 + n) * 40 + q * 8];
            #pragma unroll
            for (int rt = 0; rt < 2; ++rt) {
                acc[rt][ct] = __builtin_amdgcn_mfma_f32_16x16x32_bf16(af[rt][0], bh, acc[rt][ct], 0, 0, 0);
                acc[rt][ct] = __builtin_amdgcn_mfma_f32_16x16x32_bf16(af[rt][1], bh, acc[rt][ct], 0, 0, 0);
                acc[rt][ct] = __builtin_amdgcn_mfma_f32_16x16x32_bf16(af[rt][0], bl, acc[rt][ct], 0, 0, 0);
            }
        }
    }

    #pragma unroll
    for (int rt = 0; rt < 2; ++rt)
        #pragma unroll
        for (int ct = 0; ct < 8; ++ct) {
            int c = c0 + ct * 16 + n;
            float sc = 1.f, bt = 0.f;
            if (fuse_bn) { sc = g[c] / sqrtf(1.f + EPS_BN); bt = beta[c]; }
            #pragma unroll
            for (int e = 0; e < 4; ++e) {
                int m = m0 + w * 32 + rt * 16 + q * 4 + e;
                float v = acc[rt][ct][e];
                if (fuse_bn) { v = v * sc + bt; v = (v >= 0.f) ? v : SLOPE * v; }
                out[(size_t)m * C + c] = v;
            }
        }
}

// ---------------------------------------------------------------------------
// EdgeConv max-pool epilogue -> bf16 hi/lo feature rows
__global__ void pool_kernel(const float* __restrict__ zc2, int Co,
                            const int* __restrict__ idx,
                            const float* __restrict__ g, const float* __restrict__ beta,
                            unsigned short* __restrict__ hh, unsigned short* __restrict__ hl,
                            int hoff) {
    int n = blockIdx.x, b = blockIdx.y;
    int o = threadIdx.x;
    size_t bn = (size_t)b * N_PTS + n;
    const int* ip = idx + bn * KNN;
    float zn   = zc2[bn * (size_t)(2 * Co) + o];
    float base = zc2[bn * (size_t)(2 * Co) + Co + o] - zn;
    float m = -INFINITY;
    #pragma unroll
    for (int j = 0; j < KNN; ++j) {
        size_t rr = (size_t)b * N_PTS + ip[j];
        m = fmaxf(m, zc2[rr * (size_t)(2 * Co) + o]);
    }
    float y = m + base;
    float sc = g[o] / sqrtf(1.f + EPS_BN);
    y = y * sc + beta[o];
    y = (y >= 0.f) ? y : SLOPE * y;
    unsigned short h = f2bf(y);
    hh[bn * 512 + hoff + o] = h;
    hl[bn * 512 + hoff + o] = f2bf(y - bf2f(h));
}

// ---------------------------------------------------------------------------
// final global max/mean over N: two-stage (32 chunks of 128 rows)
__global__ void reduce_partial(const float* __restrict__ y5,
                               float* __restrict__ pmax, float* __restrict__ psum) {
    int chunk = blockIdx.x, b = blockIdx.y, c = threadIdx.x;
    float mx = -INFINITY, sm = 0.f;
    for (int qq = 0; qq < 128; ++qq) {
        int n = chunk * 128 + qq;
        float v = y5[((size_t)b * N_PTS + n) * 512 + c];
        mx = fmaxf(mx, v);
        sm += v;
    }
    pmax[((size_t)b * 32 + chunk) * 512 + c] = mx;
    psum[((size_t)b * 32 + chunk) * 512 + c] = sm;
}

__global__ void reduce_final(const float* __restrict__ pmax,
                             const float* __restrict__ psum,
                             float* __restrict__ out) {
    int i = blockIdx.x * blockDim.x + threadIdx.x;
    if (i >= BATCH * 512) return;
    int b = i / 512, c = i % 512;
    float mx = -INFINITY, sm = 0.f;
    for (int qq = 0; qq < 32; ++qq) {
        mx = fmaxf(mx, pmax[((size_t)b * 32 + qq) * 512 + c]);
        sm += psum[((size_t)b * 32 + qq) * 512 + c];
    }
    out[(size_t)b * 1024 + c] = mx;
    out[(size_t)b * 1024 + 512 + c] = sm * (1.f / 4096.f);
}

// ---------------------------------------------------------------------------
extern "C" void kernel_launch(void* const* d_in, const int* in_sizes, int n_in,
                              void* d_out, int out_size, void* d_ws, size_t ws_size,
                              hipStream_t stream) {
    const float* x = (const float*)d_in[0];
    const float* W[5], *gg[5], *bb[5];
    for (int i = 0; i < 5; ++i) {
        W[i]  = (const float*)d_in[2 + 3 * i];
        gg[i] = (const float*)d_in[3 + 3 * i];
        bb[i] = (const float*)d_in[4 + 3 * i];
    }
    float* outp = (float*)d_out;

    char* wsb = (char*)d_ws;
    size_t off = 0;
    unsigned short* x1h = (unsigned short*)(wsb + off); off += (size_t)M_ROWS * 32 * 2;
    unsigned short* x1l = (unsigned short*)(wsb + off); off += (size_t)M_ROWS * 32 * 2;
    float* sq = (float*)(wsb + off); off += (size_t)M_ROWS * 4;
    int*   idx = (int*)(wsb + off); off += (size_t)M_ROWS * KNN * 4;
    unsigned short* Wh = (unsigned short*)(wsb + off); off += (size_t)512 * 512 * 2;
    unsigned short* Wl = (unsigned short*)(wsb + off); off += (size_t)512 * 512 * 2;
    unsigned short* hh = (unsigned short*)(wsb + off); off += (size_t)M_ROWS * 512 * 2;
    unsigned short* hl = (unsigned short*)(wsb + off); off += (size_t)M_ROWS * 512 * 2;
    float* zc2 = (float*)(wsb + off); off += (size_t)M_ROWS * 512 * 4;
    float* pmx = (float*)(wsb + off); off += (size_t)BATCH * 32 * 512 * 4;
    float* psm = (float*)(wsb + off); off += (size_t)BATCH * 32 * 512 * 4;
    (void)ws_size; (void)in_sizes; (void)n_in; (void)out_size;

    convert_x1<<<(M_ROWS + 255) / 256, 256, 0, stream>>>(x, x1h, x1l, sq);

    struct L { int D, Co, KP, hoff; };
    const L layers[4] = { {3, 64, 32, 0}, {64, 64, 64, 64}, {64, 128, 64, 128}, {128, 256, 128, 256} };

    for (int li = 0; li < 4; ++li) {
        const L& ly = layers[li];
        const unsigned short* Ahp;
        const unsigned short* Alp;
        int strideA;
        if (li == 0) { Ahp = x1h; Alp = x1l; strideA = 32; }
        else {
            int po = layers[li - 1].hoff;
            Ahp = hh + po; Alp = hl + po; strideA = 512;
            sqnorm_hl<<<M_ROWS / 4, 256, 0, stream>>>(Ahp, Alp, ly.D, sq);
        }

        if (li == 0)
            knn_mfma<32><<<dim3(N_PTS / 64, BATCH), 256, 0, stream>>>(Ahp, Alp, strideA, sq, idx);
        else if (ly.D == 64)
            knn_mfma<64><<<dim3(N_PTS / 64, BATCH), 256, 0, stream>>>(Ahp, Alp, strideA, sq, idx);
        else
            knn_mfma<128><<<dim3(N_PTS / 64, BATCH), 256, 0, stream>>>(Ahp, Alp, strideA, sq, idx);

        repack_edge_split<<<(2 * ly.Co * ly.KP + 255) / 256, 256, 0, stream>>>(
            W[li], ly.Co, ly.D, ly.KP, Wh, Wl);
        fgemm<<<dim3((2 * ly.Co) / 128, M_ROWS / 128), 256, 0, stream>>>(
            Ahp, Alp, strideA, ly.KP, Wh, Wl, 2 * ly.Co, zc2, 0, nullptr, nullptr);
        pool_kernel<<<dim3(N_PTS, BATCH), ly.Co, 0, stream>>>(
            zc2, ly.Co, idx, gg[li], bb[li], hh, hl, ly.hoff);
    }

    // layer 5
    repack_w5_split<<<(512 * 512 + 255) / 256, 256, 0, stream>>>(W[4], Wh, Wl);
    fgemm<<<dim3(4, M_ROWS / 128), 256, 0, stream>>>(
        hh, hl, 512, 512, Wh, Wl, 512, zc2, 1, gg[4], bb[4]);

    reduce_partial<<<dim3(32, BATCH), 512, 0, stream>>>(zc2, pmx, psm);
    reduce_final<<<(BATCH * 512 + 255) / 256, 256, 0, stream>>>(pmx, psm, outp);
}